// Round 11
// baseline (176.152 us; speedup 1.0000x reference)
//
#include <hip/hip_runtime.h>
#include <cstdint>

#define EMBD 1024
#define NH 16
#define DH 64
#define BB 2
#define SS 2048
#define M_TOT (BB*SS)     // 4096
#define N_QKV (3*EMBD)    // 3072

typedef __bf16 bf16_t;
typedef bf16_t bf16x8 __attribute__((ext_vector_type(8)));
typedef float f32x4 __attribute__((ext_vector_type(4)));
typedef unsigned short u16;
typedef unsigned int u32;

static __device__ __forceinline__ u16 f2bf(float f) {
    union { float f; unsigned u; } c; c.f = f;
    unsigned u = c.u;
    unsigned r = (u + 0x7FFFu + ((u >> 16) & 1u)) >> 16;  // RNE
    return (u16)r;
}

// async global->LDS, 16B per lane; LDS dest must be wave-uniform base + lane*16
#define GLDS16(gp, lp) \
    __builtin_amdgcn_global_load_lds((const __attribute__((address_space(1))) void*)(gp), \
                                     (__attribute__((address_space(3))) void*)(lp), 16, 0, 0)

// ---------------- fused cast fp32 -> bf16 for x, W_in, W_out ----------------
#define NX8 (M_TOT * EMBD / 8)          // 524288
#define NWI8 (N_QKV * EMBD / 8)         // 393216
#define NWO8 (EMBD * EMBD / 8)          // 131072
__global__ void cast_all(const float* __restrict__ x, const float* __restrict__ wi,
                         const float* __restrict__ wo, u16* __restrict__ xb,
                         u16* __restrict__ wib, u16* __restrict__ wob) {
    int i = blockIdx.x * blockDim.x + threadIdx.x;
    const float* s; u16* d; int off;
    if (i < NX8)              { s = x;  d = xb;  off = i; }
    else if (i < NX8 + NWI8)  { s = wi; d = wib; off = i - NX8; }
    else                      { s = wo; d = wob; off = i - NX8 - NWI8; }
    const float4* s4 = (const float4*)s;
    float4 a = s4[2 * off];
    float4 b = s4[2 * off + 1];
    union { u16 u[8]; uint4 v; } r;
    r.u[0] = f2bf(a.x); r.u[1] = f2bf(a.y); r.u[2] = f2bf(a.z); r.u[3] = f2bf(a.w);
    r.u[4] = f2bf(b.x); r.u[5] = f2bf(b.y); r.u[6] = f2bf(b.z); r.u[7] = f2bf(b.w);
    ((uint4*)d)[off] = r.v;
}

// ---------------- QKV GEMM: ring-3 DMA pipeline, vmcnt(4) (R3-proven) -------
// Epilogue layouts (attn-verified, BANK-SWIZZLED for attn's LDS reads):
//   Q  [B,H,S,64] row-major, scaled by 0.125*log2(e)
//   Kf: off = tile*1024 + (d>>5)*512 + (key&15)*32 + (((d>>3)&3)^((key>>1)&3))*8 + (d&7)
//   Vpf: p = (((s>>2)&3) ^ ((d>>1)&3))*8 + ((s>>4)&1)*4 + (s&3)
//        off = (s>>5)*2048 + (d>>4)*512 + (d&15)*32 + p
#define QSCALE (0.125f * 1.4426950408889634f)
__global__ __launch_bounds__(256) void gemm_qkv(
    const u16* __restrict__ Xb,   // [4096][1024]
    const u16* __restrict__ Wb,   // [3072][1024]
    const float* __restrict__ b_in,
    u16* __restrict__ Q, u16* __restrict__ Kf, u16* __restrict__ Vpf)
{
    __shared__ u16 AB[3][8192];   // [buf][A 4096 | B 4096]  48 KB (3 blocks/CU)
    const int t = threadIdx.x;
    const int lane = t & 63;
    const int wave = t >> 6;
    const int wm = wave >> 1, wn = wave & 1;
    const int quad = lane >> 4, l16 = lane & 15;
    const int m0 = blockIdx.y * 128, n0 = blockIdx.x * 128;

    const int s0i = t, s1i = 256 + t;
    const u16* ga0 = Xb + (size_t)(m0 + (s0i >> 2)) * EMBD + (s0i & 3) * 8;
    const u16* ga1 = Xb + (size_t)(m0 + (s1i >> 2)) * EMBD + (s1i & 3) * 8;
    const u16* gb0 = Wb + (size_t)(n0 + (s0i >> 2)) * EMBD + (s0i & 3) * 8;
    const u16* gb1 = Wb + (size_t)(n0 + (s1i >> 2)) * EMBD + (s1i & 3) * 8;

    f32x4 acc[4][4] = {};

    // prologue: DMA k-tiles 0 and 1 into bufs 0,1
#pragma unroll
    for (int p = 0; p < 2; ++p) {
        u16* buf = &AB[p][0];
        GLDS16(ga0 + p * 32, buf + s0i * 8);
        GLDS16(ga1 + p * 32, buf + s1i * 8);
        GLDS16(gb0 + p * 32, buf + 4096 + s0i * 8);
        GLDS16(gb1 + p * 32, buf + 4096 + s1i * 8);
    }

    int bi = 0;                    // buffer index = it % 3
    int bw = 2;                    // buffer index for it+2
    for (int it = 0; it < EMBD / 32; ++it) {
        asm volatile("s_waitcnt vmcnt(4)" ::: "memory");
        __syncthreads();
        {   // always-issue tile it+2 (trailing OOB prefetches are benign:
            // reads land inside ws, writes go to bufs never read again)
            int k0 = (it + 2) * 32;
            u16* buf = &AB[bw][0];
            GLDS16(ga0 + k0, buf + s0i * 8);
            GLDS16(ga1 + k0, buf + s1i * 8);
            GLDS16(gb0 + k0, buf + 4096 + s0i * 8);
            GLDS16(gb1 + k0, buf + 4096 + s1i * 8);
        }
        const u16* As = &AB[bi][0];
        const u16* Bs = &AB[bi][4096];
        bf16x8 af[4], bfr[4];
#pragma unroll
        for (int im = 0; im < 4; ++im)
            af[im] = *(const bf16x8*)(As + (wm * 64 + im * 16 + l16) * 32 + quad * 8);
#pragma unroll
        for (int in = 0; in < 4; ++in)
            bfr[in] = *(const bf16x8*)(Bs + (wn * 64 + in * 16 + l16) * 32 + quad * 8);
#pragma unroll
        for (int im = 0; im < 4; ++im)
#pragma unroll
            for (int in = 0; in < 4; ++in)
                acc[im][in] = __builtin_amdgcn_mfma_f32_16x16x32_bf16(
                    af[im], bfr[in], acc[im][in], 0, 0, 0);
        bi = (bi == 2) ? 0 : bi + 1;
        bw = (bw == 2) ? 0 : bw + 1;
    }

    // epilogue: C/D layout col=lane&15, row=quad*4+reg
#pragma unroll
    for (int im = 0; im < 4; ++im) {
        int rbase = m0 + wm * 64 + im * 16 + quad * 4;
        int b = rbase >> 11, ss = rbase & (SS - 1);     // ss%4==0, keys ss..ss+3
#pragma unroll
        for (int in = 0; in < 4; ++in) {
            int col = n0 + wn * 64 + in * 16 + l16;
            float bias = b_in[col];
            float v0 = acc[im][in][0] + bias;
            float v1 = acc[im][in][1] + bias;
            float v2 = acc[im][in][2] + bias;
            float v3 = acc[im][in][3] + bias;
            if (col < EMBD) {
                int h = col >> 6, d = col & 63;
                u16* qp = Q + (((size_t)(b * NH + h) * SS) + ss) * DH + d;
                qp[0]      = f2bf(v0 * QSCALE);
                qp[DH]     = f2bf(v1 * QSCALE);
                qp[2 * DH] = f2bf(v2 * QSCALE);
                qp[3 * DH] = f2bf(v3 * QSCALE);
            } else if (col < 2 * EMBD) {
                int c = col - EMBD; int h = c >> 6, d = c & 63;
                int qf = (d >> 3) & 3;                 // 16B-slot field
                int sA = (ss >> 1) & 3;                // keys ss, ss+1 (ss%4==0)
                int sB = (sA + 1) & 3;                 // keys ss+2, ss+3
                u16* kp = Kf + (size_t)(b * NH + h) * SS * DH
                          + (ss >> 4) * 1024 + (d >> 5) * 512
                          + (ss & 15) * 32 + (d & 7);
                kp[(qf ^ sA) * 8]      = f2bf(v0);
                kp[32 + (qf ^ sA) * 8] = f2bf(v1);
                kp[64 + (qf ^ sB) * 8] = f2bf(v2);
                kp[96 + (qf ^ sB) * 8] = f2bf(v3);
            } else {
                int c = col - 2 * EMBD; int h = c >> 6, d = c & 63;
                int p32 = ((((ss >> 2) & 3) ^ ((d >> 1) & 3)) * 8)
                          + ((ss >> 4) & 1) * 4;       // + j for key ss+j
                u32 lo = (u32)f2bf(v0) | ((u32)f2bf(v1) << 16);
                u32 hi = (u32)f2bf(v2) | ((u32)f2bf(v3) << 16);
                uint2 pk; pk.x = lo; pk.y = hi;
                *(uint2*)(Vpf + (size_t)(b * NH + h) * SS * DH
                          + (ss >> 5) * 2048 + (d >> 4) * 512 + (d & 15) * 32 + p32) = pk;
            }
        }
    }
}

// ---------------- attention v11 (R3-proven): ring-3, per-iter barrier -------
// NOTE (R9 lesson): the per-iteration barrier is load-bearing for READ
// readiness — vmcnt is per-wave, so only the barrier makes all waves' DMA
// completions mutually visible. Do not thin it.
#define OST 72
#define NCH (SS / 64)     // 32 chunks
__global__ __launch_bounds__(256, 2) void attn(
    const u16* __restrict__ Q, const u16* __restrict__ Kf,
    const u16* __restrict__ Vpf, u16* __restrict__ AO)
{
    __shared__ u16 KV[3][8192];     // 48 KB ring-3
    const int t = threadIdx.x;
    const int lane = t & 63, w = t >> 6;
    const int quad = lane >> 4, l16 = lane & 15;
    const int sq8 = (quad ^ ((l16 >> 1) & 3)) * 8;   // swizzled 16B slot
    const int b0 = blockIdx.x;
    const int bh = (b0 & 7) * 4 + ((b0 >> 3) & 3);   // XCD-clustered heads
    const int qt = b0 >> 5;
    const int q0 = qt * 128 + w * 32;

    const u16* Qh = Q + ((size_t)bh * SS + q0) * DH;
    const u16* Kh = Kf + (size_t)bh * SS * DH;
    const u16* Vh = Vpf + (size_t)bh * SS * DH;

    bf16x8 qb[2][2];
#pragma unroll
    for (int qi = 0; qi < 2; ++qi) {
        qb[qi][0] = *(const bf16x8*)(Qh + (qi * 16 + l16) * DH + quad * 8);
        qb[qi][1] = *(const bf16x8*)(Qh + (qi * 16 + l16) * DH + 32 + quad * 8);
    }

    union { u16 u[8]; bf16x8 b; } onesu;
#pragma unroll
    for (int j = 0; j < 8; ++j) onesu.u[j] = 0x3F80u;
    const bf16x8 ones = onesu.b;

    f32x4 o[2][4] = {};
    f32x4 ol[2] = {};

    // prologue: chunks 0,1 -> slots 0,1 (4 DMAs each)
#pragma unroll
    for (int p = 0; p < 2; ++p) {
        GLDS16(Kh + p * 4096 + t * 8,        &KV[p][0] + t * 8);
        GLDS16(Kh + p * 4096 + 2048 + t * 8, &KV[p][0] + 2048 + t * 8);
        GLDS16(Vh + p * 4096 + t * 8,        &KV[p][4096] + t * 8);
        GLDS16(Vh + p * 4096 + 2048 + t * 8, &KV[p][4096] + 2048 + t * 8);
    }

    int bi = 0, bw = 2;
    for (int it = 0; it < NCH; ++it) {
        asm volatile("s_waitcnt vmcnt(4)" ::: "memory");
        __syncthreads();
        if (it < NCH - 1) {         // skip last issue: slot 0 aliases staging
            const u16* kc = Kh + (it + 2) * 4096;   // it=30 -> OOB read, benign (ws)
            const u16* vc = Vh + (it + 2) * 4096;
            u16* kb = &KV[bw][0];
            u16* vb = &KV[bw][4096];
            GLDS16(kc + t * 8,        kb + t * 8);
            GLDS16(kc + 2048 + t * 8, kb + 2048 + t * 8);
            GLDS16(vc + t * 8,        vb + t * 8);
            GLDS16(vc + 2048 + t * 8, vb + 2048 + t * 8);
        }
        const u16* Kb = &KV[bi][0];
        const u16* Vb = &KV[bi][4096];
#pragma unroll
        for (int g = 0; g < 2; ++g) {    // 2 groups of 32 keys
            bf16x8 ka00 = *(const bf16x8*)(Kb + (2 * g) * 1024 +       l16 * 32 + sq8);
            bf16x8 ka01 = *(const bf16x8*)(Kb + (2 * g) * 1024 + 512 + l16 * 32 + sq8);
            bf16x8 ka10 = *(const bf16x8*)(Kb + (2 * g + 1) * 1024 +       l16 * 32 + sq8);
            bf16x8 ka11 = *(const bf16x8*)(Kb + (2 * g + 1) * 1024 + 512 + l16 * 32 + sq8);
            bf16x8 va0 = *(const bf16x8*)(Vb + g * 2048 +        l16 * 32 + sq8);
            bf16x8 va1 = *(const bf16x8*)(Vb + g * 2048 + 512  + l16 * 32 + sq8);
            bf16x8 va2 = *(const bf16x8*)(Vb + g * 2048 + 1024 + l16 * 32 + sq8);
            bf16x8 va3 = *(const bf16x8*)(Vb + g * 2048 + 1536 + l16 * 32 + sq8);
            bf16x8 pb[2];
#pragma unroll
            for (int qi = 0; qi < 2; ++qi) {
                f32x4 z0 = {0.f, 0.f, 0.f, 0.f};
                f32x4 z1 = {0.f, 0.f, 0.f, 0.f};
                __builtin_amdgcn_s_setprio(1);
                z0 = __builtin_amdgcn_mfma_f32_16x16x32_bf16(ka00, qb[qi][0], z0, 0, 0, 0);
                z0 = __builtin_amdgcn_mfma_f32_16x16x32_bf16(ka01, qb[qi][1], z0, 0, 0, 0);
                z1 = __builtin_amdgcn_mfma_f32_16x16x32_bf16(ka10, qb[qi][0], z1, 0, 0, 0);
                z1 = __builtin_amdgcn_mfma_f32_16x16x32_bf16(ka11, qb[qi][1], z1, 0, 0, 0);
                __builtin_amdgcn_s_setprio(0);
                u32 ue[8];
#pragma unroll
                for (int j = 0; j < 4; ++j) {
                    float e0 = __builtin_amdgcn_exp2f(z0[j]);
                    float e1 = __builtin_amdgcn_exp2f(z1[j]);
                    union { float f; u32 v; } c0, c1;
                    c0.f = e0; c1.f = e1;
                    ue[j] = c0.v + 0x8000u;      // round-half-up to bf16
                    ue[4 + j] = c1.v + 0x8000u;
                }
                union { uint4 u; bf16x8 b; } cv;
                cv.u.x = __builtin_amdgcn_perm(ue[1], ue[0], 0x07060302u);
                cv.u.y = __builtin_amdgcn_perm(ue[3], ue[2], 0x07060302u);
                cv.u.z = __builtin_amdgcn_perm(ue[5], ue[4], 0x07060302u);
                cv.u.w = __builtin_amdgcn_perm(ue[7], ue[6], 0x07060302u);
                pb[qi] = cv.b;
            }
            __builtin_amdgcn_s_setprio(1);
            o[0][0] = __builtin_amdgcn_mfma_f32_16x16x32_bf16(va0, pb[0], o[0][0], 0, 0, 0);
            o[0][1] = __builtin_amdgcn_mfma_f32_16x16x32_bf16(va1, pb[0], o[0][1], 0, 0, 0);
            o[0][2] = __builtin_amdgcn_mfma_f32_16x16x32_bf16(va2, pb[0], o[0][2], 0, 0, 0);
            o[0][3] = __builtin_amdgcn_mfma_f32_16x16x32_bf16(va3, pb[0], o[0][3], 0, 0, 0);
            ol[0]   = __builtin_amdgcn_mfma_f32_16x16x32_bf16(ones, pb[0], ol[0], 0, 0, 0);
            o[1][0] = __builtin_amdgcn_mfma_f32_16x16x32_bf16(va0, pb[1], o[1][0], 0, 0, 0);
            o[1][1] = __builtin_amdgcn_mfma_f32_16x16x32_bf16(va1, pb[1], o[1][1], 0, 0, 0);
            o[1][2] = __builtin_amdgcn_mfma_f32_16x16x32_bf16(va2, pb[1], o[1][2], 0, 0, 0);
            o[1][3] = __builtin_amdgcn_mfma_f32_16x16x32_bf16(va3, pb[1], o[1][3], 0, 0, 0);
            ol[1]   = __builtin_amdgcn_mfma_f32_16x16x32_bf16(ones, pb[1], ol[1], 0, 0, 0);
            __builtin_amdgcn_s_setprio(0);
        }
        bi = (bi == 2) ? 0 : bi + 1;
        bw = (bw == 2) ? 0 : bw + 1;
    }

    float rl[2];
    rl[0] = 1.0f / ol[0][0];
    rl[1] = 1.0f / ol[1][0];
    __syncthreads();
    // Ksc spans KV flat [0..9216) u16; in-flight chunk-32 DMAs (if any) write
    // slot 2 [16384..) -> disjoint.
    u16* Ksc = &KV[0][0];
#pragma unroll
    for (int qi = 0; qi < 2; ++qi)
#pragma unroll
        for (int dt = 0; dt < 4; ++dt)
#pragma unroll
            for (int jj = 0; jj < 2; ++jj) {
                u32 lo_ = (u32)f2bf(o[qi][dt][2 * jj] * rl[qi]);
                u32 hi_ = (u32)f2bf(o[qi][dt][2 * jj + 1] * rl[qi]);
                *(u32*)(Ksc + (w * 32 + qi * 16 + l16) * OST + dt * 16 + quad * 4 + jj * 2) =
                    lo_ | (hi_ << 16);
            }
    __syncthreads();
    const int b = bh >> 4, h = bh & 15;
#pragma unroll
    for (int i = 0; i < 4; ++i) {
        int idx = i * 256 + t;
        int q = idx >> 3, c = idx & 7;
        uint4 vv = *(const uint4*)(Ksc + q * OST + c * 8);
        *(uint4*)(AO + ((size_t)(b * SS + qt * 128 + q)) * EMBD + h * DH + c * 8) = vv;
    }
}

// ---------------- out projection GEMM: 128x64 tile, BK=64, ring-3, swizzled -
// (R8-proven: 16 K-iterations, 6 DMAs/iter, vmcnt(6), 8-slot row swizzle.)
__global__ __launch_bounds__(256) void gemm_out(
    const u16* __restrict__ Ab,   // [4096][1024]
    const u16* __restrict__ Wb,   // [1024][1024]
    const float* __restrict__ b_out,
    float* __restrict__ Out)
{
    __shared__ u16 AB[3][12288];  // [slot][A 8192 | B 4096]  72 KB (2 blocks/CU)
    const int t = threadIdx.x;
    const int lane = t & 63;
    const int wave = t >> 6;       // wave = M-row group (4x32 rows)
    const int quad = lane >> 4, l16 = lane & 15;
    const int m0 = blockIdx.y * 128, n0 = blockIdx.x * 64;

    // staging: row = i*32 + (t>>3); source slot = (t&7) ^ ((t>>3)&7)
    const int srow = t >> 3;
    const int scol = ((t & 7) ^ (srow & 7)) * 8;
    const u16* gaA[4];
#pragma unroll
    for (int i = 0; i < 4; ++i)
        gaA[i] = Ab + (size_t)(m0 + i * 32 + srow) * EMBD + scol;
    const u16* gbB[2];
#pragma unroll
    for (int i = 0; i < 2; ++i)
        gbB[i] = Wb + (size_t)(n0 + i * 32 + srow) * EMBD + scol;

    f32x4 acc[2][4] = {};

    // prologue: k-tiles 0,1 -> slots 0,1 (6 DMAs each)
#pragma unroll
    for (int p = 0; p < 2; ++p) {
        u16* buf = &AB[p][0];
#pragma unroll
        for (int i = 0; i < 4; ++i)
            GLDS16(gaA[i] + p * 64, buf + i * 2048 + t * 8);
#pragma unroll
        for (int i = 0; i < 2; ++i)
            GLDS16(gbB[i] + p * 64, buf + 8192 + i * 2048 + t * 8);
    }

    int bi = 0, bw = 2;
    for (int it = 0; it < EMBD / 64; ++it) {
        asm volatile("s_waitcnt vmcnt(6)" ::: "memory");
        __syncthreads();
        {   // always-issue tile it+2 (trailing OOB reads stay inside ws: benign)
            int k0 = (it + 2) * 64;
            u16* buf = &AB[bw][0];
#pragma unroll
            for (int i = 0; i < 4; ++i)
                GLDS16(gaA[i] + k0, buf + i * 2048 + t * 8);
#pragma unroll
            for (int i = 0; i < 2; ++i)
                GLDS16(gbB[i] + k0, buf + 8192 + i * 2048 + t * 8);
        }
        const u16* As = &AB[bi][0];
        const u16* Bs = &AB[bi][8192];
        bf16x8 af[2][2], bfr[4][2];
#pragma unroll
        for (int im = 0; im < 2; ++im)
#pragma unroll
            for (int kk = 0; kk < 2; ++kk)
                af[im][kk] = *(const bf16x8*)(As + (wave * 32 + im * 16 + l16) * 64
                                              + (((kk * 4 + quad) ^ (l16 & 7)) * 8));
#pragma unroll
        for (int in = 0; in < 4; ++in)
#pragma unroll
            for (int kk = 0; kk < 2; ++kk)
                bfr[in][kk] = *(const bf16x8*)(Bs + (in * 16 + l16) * 64
                                               + (((kk * 4 + quad) ^ (l16 & 7)) * 8));
#pragma unroll
        for (int im = 0; im < 2; ++im)
#pragma unroll
            for (int in = 0; in < 4; ++in)
#pragma unroll
                for (int kk = 0; kk < 2; ++kk)
                    acc[im][in] = __builtin_amdgcn_mfma_f32_16x16x32_bf16(
                        af[im][kk], bfr[in][kk], acc[im][in], 0, 0, 0);
        bi = (bi == 2) ? 0 : bi + 1;
        bw = (bw == 2) ? 0 : bw + 1;
    }

#pragma unroll
    for (int im = 0; im < 2; ++im) {
        int rbase = m0 + wave * 32 + im * 16 + quad * 4;
#pragma unroll
        for (int in = 0; in < 4; ++in) {
            int col = n0 + in * 16 + l16;
            float bias = b_out[col];
#pragma unroll
            for (int j = 0; j < 4; ++j)
                Out[(size_t)(rbase + j) * EMBD + col] = acc[im][in][j] + bias;
        }
    }
}

extern "C" void kernel_launch(void* const* d_in, const int* in_sizes, int n_in,
                              void* d_out, int out_size, void* d_ws, size_t ws_size,
                              hipStream_t stream)
{
    (void)in_sizes; (void)n_in; (void)out_size; (void)ws_size;
    const float* x     = (const float*)d_in[0];
    const float* W_in  = (const float*)d_in[1];
    const float* b_in  = (const float*)d_in[2];
    const float* W_out = (const float*)d_in[3];
    const float* b_out = (const float*)d_in[4];
    float* out = (float*)d_out;

    char* ws = (char*)d_ws;
    u16* xb  = (u16*)(ws);                          //  8 MB: x bf16 [4096][1024]
    u16* wib = (u16*)(ws + 8u  * 1024 * 1024);      //  6 MB: W_in bf16
    u16* wob = (u16*)(ws + 14u * 1024 * 1024);      //  2 MB: W_out bf16
    u16* Qw  = (u16*)(ws + 16u * 1024 * 1024);      //  8 MB: Q (x log2e/8)
    u16* Kw  = (u16*)(ws + 24u * 1024 * 1024);      //  8 MB: Kf fragment-linear
    u16* Vpw = (u16*)(ws + 32u * 1024 * 1024);      //  8 MB: Vpf frag-linear permuted
    u16* AO  = (u16*)(ws + 40u * 1024 * 1024);      //  8 MB: attn out bf16

    cast_all<<<(NX8 + NWI8 + NWO8) / 256, 256, 0, stream>>>(x, W_in, W_out, xb, wib, wob);
    gemm_qkv<<<dim3(N_QKV / 128, M_TOT / 128), 256, 0, stream>>>(xb, wib, b_in, Qw, Kw, Vpw);
    attn<<<512, 256, 0, stream>>>(Qw, Kw, Vpw, AO);
    gemm_out<<<dim3(EMBD / 64, M_TOT / 128), 256, 0, stream>>>(AO, wob, b_out, out);
}

// Round 12
// 171.188 us; speedup vs baseline: 1.0290x; 1.0290x over previous
//
#include <hip/hip_runtime.h>
#include <cstdint>

#define EMBD 1024
#define NH 16
#define DH 64
#define BB 2
#define SS 2048
#define M_TOT (BB*SS)     // 4096
#define N_QKV (3*EMBD)    // 3072

typedef __bf16 bf16_t;
typedef bf16_t bf16x8 __attribute__((ext_vector_type(8)));
typedef float f32x4 __attribute__((ext_vector_type(4)));
typedef unsigned short u16;
typedef unsigned int u32;

static __device__ __forceinline__ u16 f2bf(float f) {
    union { float f; unsigned u; } c; c.f = f;
    unsigned u = c.u;
    unsigned r = (u + 0x7FFFu + ((u >> 16) & 1u)) >> 16;  // RNE
    return (u16)r;
}

// async global->LDS, 16B per lane; LDS dest must be wave-uniform base + lane*16
#define GLDS16(gp, lp) \
    __builtin_amdgcn_global_load_lds((const __attribute__((address_space(1))) void*)(gp), \
                                     (__attribute__((address_space(3))) void*)(lp), 16, 0, 0)

// ---------------- fused cast fp32 -> bf16 for x, W_in, W_out ----------------
#define NX8 (M_TOT * EMBD / 8)          // 524288
#define NWI8 (N_QKV * EMBD / 8)         // 393216
#define NWO8 (EMBD * EMBD / 8)          // 131072
__global__ void cast_all(const float* __restrict__ x, const float* __restrict__ wi,
                         const float* __restrict__ wo, u16* __restrict__ xb,
                         u16* __restrict__ wib, u16* __restrict__ wob) {
    int i = blockIdx.x * blockDim.x + threadIdx.x;
    const float* s; u16* d; int off;
    if (i < NX8)              { s = x;  d = xb;  off = i; }
    else if (i < NX8 + NWI8)  { s = wi; d = wib; off = i - NX8; }
    else                      { s = wo; d = wob; off = i - NX8 - NWI8; }
    const float4* s4 = (const float4*)s;
    float4 a = s4[2 * off];
    float4 b = s4[2 * off + 1];
    union { u16 u[8]; uint4 v; } r;
    r.u[0] = f2bf(a.x); r.u[1] = f2bf(a.y); r.u[2] = f2bf(a.z); r.u[3] = f2bf(a.w);
    r.u[4] = f2bf(b.x); r.u[5] = f2bf(b.y); r.u[6] = f2bf(b.z); r.u[7] = f2bf(b.w);
    ((uint4*)d)[off] = r.v;
}

// ---------------- QKV GEMM: ring-3 DMA pipeline, vmcnt(4) (R3-proven) -------
// Epilogue layouts (attn-verified, BANK-SWIZZLED for attn's LDS reads):
//   Q  [B,H,S,64] row-major, scaled by 0.125*log2(e)
//   Kf: off = tile*1024 + (d>>5)*512 + (key&15)*32 + (((d>>3)&3)^((key>>1)&3))*8 + (d&7)
//   Vpf: p = (((s>>2)&3) ^ ((d>>1)&3))*8 + ((s>>4)&1)*4 + (s&3)
//        off = (s>>5)*2048 + (d>>4)*512 + (d&15)*32 + p
#define QSCALE (0.125f * 1.4426950408889634f)
__global__ __launch_bounds__(256) void gemm_qkv(
    const u16* __restrict__ Xb,   // [4096][1024]
    const u16* __restrict__ Wb,   // [3072][1024]
    const float* __restrict__ b_in,
    u16* __restrict__ Q, u16* __restrict__ Kf, u16* __restrict__ Vpf)
{
    __shared__ u16 AB[3][8192];   // [buf][A 4096 | B 4096]  48 KB (3 blocks/CU)
    const int t = threadIdx.x;
    const int lane = t & 63;
    const int wave = t >> 6;
    const int wm = wave >> 1, wn = wave & 1;
    const int quad = lane >> 4, l16 = lane & 15;
    const int m0 = blockIdx.y * 128, n0 = blockIdx.x * 128;

    const int s0i = t, s1i = 256 + t;
    const u16* ga0 = Xb + (size_t)(m0 + (s0i >> 2)) * EMBD + (s0i & 3) * 8;
    const u16* ga1 = Xb + (size_t)(m0 + (s1i >> 2)) * EMBD + (s1i & 3) * 8;
    const u16* gb0 = Wb + (size_t)(n0 + (s0i >> 2)) * EMBD + (s0i & 3) * 8;
    const u16* gb1 = Wb + (size_t)(n0 + (s1i >> 2)) * EMBD + (s1i & 3) * 8;

    f32x4 acc[4][4] = {};

    // prologue: DMA k-tiles 0 and 1 into bufs 0,1
#pragma unroll
    for (int p = 0; p < 2; ++p) {
        u16* buf = &AB[p][0];
        GLDS16(ga0 + p * 32, buf + s0i * 8);
        GLDS16(ga1 + p * 32, buf + s1i * 8);
        GLDS16(gb0 + p * 32, buf + 4096 + s0i * 8);
        GLDS16(gb1 + p * 32, buf + 4096 + s1i * 8);
    }

    int bi = 0;                    // buffer index = it % 3
    int bw = 2;                    // buffer index for it+2
    for (int it = 0; it < EMBD / 32; ++it) {
        asm volatile("s_waitcnt vmcnt(4)" ::: "memory");
        __syncthreads();
        {   // always-issue tile it+2 (trailing OOB prefetches are benign:
            // reads land inside ws, writes go to bufs never read again)
            int k0 = (it + 2) * 32;
            u16* buf = &AB[bw][0];
            GLDS16(ga0 + k0, buf + s0i * 8);
            GLDS16(ga1 + k0, buf + s1i * 8);
            GLDS16(gb0 + k0, buf + 4096 + s0i * 8);
            GLDS16(gb1 + k0, buf + 4096 + s1i * 8);
        }
        const u16* As = &AB[bi][0];
        const u16* Bs = &AB[bi][4096];
        bf16x8 af[4], bfr[4];
#pragma unroll
        for (int im = 0; im < 4; ++im)
            af[im] = *(const bf16x8*)(As + (wm * 64 + im * 16 + l16) * 32 + quad * 8);
#pragma unroll
        for (int in = 0; in < 4; ++in)
            bfr[in] = *(const bf16x8*)(Bs + (wn * 64 + in * 16 + l16) * 32 + quad * 8);
#pragma unroll
        for (int im = 0; im < 4; ++im)
#pragma unroll
            for (int in = 0; in < 4; ++in)
                acc[im][in] = __builtin_amdgcn_mfma_f32_16x16x32_bf16(
                    af[im], bfr[in], acc[im][in], 0, 0, 0);
        bi = (bi == 2) ? 0 : bi + 1;
        bw = (bw == 2) ? 0 : bw + 1;
    }

    // epilogue: C/D layout col=lane&15, row=quad*4+reg
#pragma unroll
    for (int im = 0; im < 4; ++im) {
        int rbase = m0 + wm * 64 + im * 16 + quad * 4;
        int b = rbase >> 11, ss = rbase & (SS - 1);     // ss%4==0, keys ss..ss+3
#pragma unroll
        for (int in = 0; in < 4; ++in) {
            int col = n0 + wn * 64 + in * 16 + l16;
            float bias = b_in[col];
            float v0 = acc[im][in][0] + bias;
            float v1 = acc[im][in][1] + bias;
            float v2 = acc[im][in][2] + bias;
            float v3 = acc[im][in][3] + bias;
            if (col < EMBD) {
                int h = col >> 6, d = col & 63;
                u16* qp = Q + (((size_t)(b * NH + h) * SS) + ss) * DH + d;
                qp[0]      = f2bf(v0 * QSCALE);
                qp[DH]     = f2bf(v1 * QSCALE);
                qp[2 * DH] = f2bf(v2 * QSCALE);
                qp[3 * DH] = f2bf(v3 * QSCALE);
            } else if (col < 2 * EMBD) {
                int c = col - EMBD; int h = c >> 6, d = c & 63;
                int qf = (d >> 3) & 3;                 // 16B-slot field
                int sA = (ss >> 1) & 3;                // keys ss, ss+1 (ss%4==0)
                int sB = (sA + 1) & 3;                 // keys ss+2, ss+3
                u16* kp = Kf + (size_t)(b * NH + h) * SS * DH
                          + (ss >> 4) * 1024 + (d >> 5) * 512
                          + (ss & 15) * 32 + (d & 7);
                kp[(qf ^ sA) * 8]      = f2bf(v0);
                kp[32 + (qf ^ sA) * 8] = f2bf(v1);
                kp[64 + (qf ^ sB) * 8] = f2bf(v2);
                kp[96 + (qf ^ sB) * 8] = f2bf(v3);
            } else {
                int c = col - 2 * EMBD; int h = c >> 6, d = c & 63;
                int p32 = ((((ss >> 2) & 3) ^ ((d >> 1) & 3)) * 8)
                          + ((ss >> 4) & 1) * 4;       // + j for key ss+j
                u32 lo = (u32)f2bf(v0) | ((u32)f2bf(v1) << 16);
                u32 hi = (u32)f2bf(v2) | ((u32)f2bf(v3) << 16);
                uint2 pk; pk.x = lo; pk.y = hi;
                *(uint2*)(Vpf + (size_t)(b * NH + h) * SS * DH
                          + (ss >> 5) * 2048 + (d >> 4) * 512 + (d & 15) * 32 + p32) = pk;
            }
        }
    }
}

// ---------------- attention v13: T15 two-deep group pipeline ---------------
// Same ring-3 + per-iter barrier sync (R9 lesson: barrier is load-bearing).
// Chunk body reordered: loads(g0,g1) -> QK(g0) -> QK(g1) -> exp(g0) ->
// PV(g0) -> exp(g1) -> PV(g1). MFMA issue doesn't block on completion, so
// exp(g0) VALU overlaps QK(g1) execution and exp(g1) overlaps PV(g0).
#define OST 72
#define NCH (SS / 64)     // 32 chunks
__global__ __launch_bounds__(256, 2) void attn(
    const u16* __restrict__ Q, const u16* __restrict__ Kf,
    const u16* __restrict__ Vpf, u16* __restrict__ AO)
{
    __shared__ u16 KV[3][8192];     // 48 KB ring-3
    const int t = threadIdx.x;
    const int lane = t & 63, w = t >> 6;
    const int quad = lane >> 4, l16 = lane & 15;
    const int sq8 = (quad ^ ((l16 >> 1) & 3)) * 8;   // swizzled 16B slot
    const int b0 = blockIdx.x;
    const int bh = (b0 & 7) * 4 + ((b0 >> 3) & 3);   // XCD-clustered heads
    const int qt = b0 >> 5;
    const int q0 = qt * 128 + w * 32;

    const u16* Qh = Q + ((size_t)bh * SS + q0) * DH;
    const u16* Kh = Kf + (size_t)bh * SS * DH;
    const u16* Vh = Vpf + (size_t)bh * SS * DH;

    bf16x8 qb[2][2];
#pragma unroll
    for (int qi = 0; qi < 2; ++qi) {
        qb[qi][0] = *(const bf16x8*)(Qh + (qi * 16 + l16) * DH + quad * 8);
        qb[qi][1] = *(const bf16x8*)(Qh + (qi * 16 + l16) * DH + 32 + quad * 8);
    }

    union { u16 u[8]; bf16x8 b; } onesu;
#pragma unroll
    for (int j = 0; j < 8; ++j) onesu.u[j] = 0x3F80u;
    const bf16x8 ones = onesu.b;

    f32x4 o[2][4] = {};
    f32x4 ol[2] = {};

    // prologue: chunks 0,1 -> slots 0,1 (4 DMAs each)
#pragma unroll
    for (int p = 0; p < 2; ++p) {
        GLDS16(Kh + p * 4096 + t * 8,        &KV[p][0] + t * 8);
        GLDS16(Kh + p * 4096 + 2048 + t * 8, &KV[p][0] + 2048 + t * 8);
        GLDS16(Vh + p * 4096 + t * 8,        &KV[p][4096] + t * 8);
        GLDS16(Vh + p * 4096 + 2048 + t * 8, &KV[p][4096] + 2048 + t * 8);
    }

    int bi = 0, bw = 2;
    for (int it = 0; it < NCH; ++it) {
        asm volatile("s_waitcnt vmcnt(4)" ::: "memory");
        __syncthreads();
        if (it < NCH - 1) {         // skip last issue: slot 0 aliases staging
            const u16* kc = Kh + (it + 2) * 4096;   // it=30 -> OOB read, benign (ws)
            const u16* vc = Vh + (it + 2) * 4096;
            u16* kb = &KV[bw][0];
            u16* vb = &KV[bw][4096];
            GLDS16(kc + t * 8,        kb + t * 8);
            GLDS16(kc + 2048 + t * 8, kb + 2048 + t * 8);
            GLDS16(vc + t * 8,        vb + t * 8);
            GLDS16(vc + 2048 + t * 8, vb + 2048 + t * 8);
        }
        const u16* Kb = &KV[bi][0];
        const u16* Vb = &KV[bi][4096];

        // ---- load ALL fragments for both 32-key groups (16 ds_read_b128) ---
        bf16x8 ka[2][4], va[2][4];
#pragma unroll
        for (int g = 0; g < 2; ++g) {
            ka[g][0] = *(const bf16x8*)(Kb + (2 * g) * 1024 +       l16 * 32 + sq8);
            ka[g][1] = *(const bf16x8*)(Kb + (2 * g) * 1024 + 512 + l16 * 32 + sq8);
            ka[g][2] = *(const bf16x8*)(Kb + (2 * g + 1) * 1024 +       l16 * 32 + sq8);
            ka[g][3] = *(const bf16x8*)(Kb + (2 * g + 1) * 1024 + 512 + l16 * 32 + sq8);
            va[g][0] = *(const bf16x8*)(Vb + g * 2048 +        l16 * 32 + sq8);
            va[g][1] = *(const bf16x8*)(Vb + g * 2048 + 512  + l16 * 32 + sq8);
            va[g][2] = *(const bf16x8*)(Vb + g * 2048 + 1024 + l16 * 32 + sq8);
            va[g][3] = *(const bf16x8*)(Vb + g * 2048 + 1536 + l16 * 32 + sq8);
        }

        // ---- QK for BOTH groups back-to-back (fills MFMA pipe) -------------
        f32x4 z[2][2][2];
        __builtin_amdgcn_s_setprio(1);
#pragma unroll
        for (int g = 0; g < 2; ++g)
#pragma unroll
            for (int qi = 0; qi < 2; ++qi) {
                f32x4 t0 = {0.f, 0.f, 0.f, 0.f};
                f32x4 t1 = {0.f, 0.f, 0.f, 0.f};
                t0 = __builtin_amdgcn_mfma_f32_16x16x32_bf16(ka[g][0], qb[qi][0], t0, 0, 0, 0);
                t0 = __builtin_amdgcn_mfma_f32_16x16x32_bf16(ka[g][1], qb[qi][1], t0, 0, 0, 0);
                t1 = __builtin_amdgcn_mfma_f32_16x16x32_bf16(ka[g][2], qb[qi][0], t1, 0, 0, 0);
                t1 = __builtin_amdgcn_mfma_f32_16x16x32_bf16(ka[g][3], qb[qi][1], t1, 0, 0, 0);
                z[g][qi][0] = t0; z[g][qi][1] = t1;
            }
        __builtin_amdgcn_s_setprio(0);

        // ---- per group: softmax (VALU) then PV (MFMA) — exp(g1) overlaps
        //      PV(g0) execution because MFMA issue doesn't block ------------
#pragma unroll
        for (int g = 0; g < 2; ++g) {
            bf16x8 pb[2];
#pragma unroll
            for (int qi = 0; qi < 2; ++qi) {
                u32 ue[8];
#pragma unroll
                for (int j = 0; j < 4; ++j) {
                    float e0 = __builtin_amdgcn_exp2f(z[g][qi][0][j]);
                    float e1 = __builtin_amdgcn_exp2f(z[g][qi][1][j]);
                    union { float f; u32 v; } c0, c1;
                    c0.f = e0; c1.f = e1;
                    ue[j] = c0.v + 0x8000u;      // round-half-up to bf16
                    ue[4 + j] = c1.v + 0x8000u;
                }
                union { uint4 u; bf16x8 b; } cv;
                cv.u.x = __builtin_amdgcn_perm(ue[1], ue[0], 0x07060302u);
                cv.u.y = __builtin_amdgcn_perm(ue[3], ue[2], 0x07060302u);
                cv.u.z = __builtin_amdgcn_perm(ue[5], ue[4], 0x07060302u);
                cv.u.w = __builtin_amdgcn_perm(ue[7], ue[6], 0x07060302u);
                pb[qi] = cv.b;
            }
            __builtin_amdgcn_s_setprio(1);
            o[0][0] = __builtin_amdgcn_mfma_f32_16x16x32_bf16(va[g][0], pb[0], o[0][0], 0, 0, 0);
            o[0][1] = __builtin_amdgcn_mfma_f32_16x16x32_bf16(va[g][1], pb[0], o[0][1], 0, 0, 0);
            o[0][2] = __builtin_amdgcn_mfma_f32_16x16x32_bf16(va[g][2], pb[0], o[0][2], 0, 0, 0);
            o[0][3] = __builtin_amdgcn_mfma_f32_16x16x32_bf16(va[g][3], pb[0], o[0][3], 0, 0, 0);
            ol[0]   = __builtin_amdgcn_mfma_f32_16x16x32_bf16(ones, pb[0], ol[0], 0, 0, 0);
            o[1][0] = __builtin_amdgcn_mfma_f32_16x16x32_bf16(va[g][0], pb[1], o[1][0], 0, 0, 0);
            o[1][1] = __builtin_amdgcn_mfma_f32_16x16x32_bf16(va[g][1], pb[1], o[1][1], 0, 0, 0);
            o[1][2] = __builtin_amdgcn_mfma_f32_16x16x32_bf16(va[g][2], pb[1], o[1][2], 0, 0, 0);
            o[1][3] = __builtin_amdgcn_mfma_f32_16x16x32_bf16(va[g][3], pb[1], o[1][3], 0, 0, 0);
            ol[1]   = __builtin_amdgcn_mfma_f32_16x16x32_bf16(ones, pb[1], ol[1], 0, 0, 0);
            __builtin_amdgcn_s_setprio(0);
        }
        bi = (bi == 2) ? 0 : bi + 1;
        bw = (bw == 2) ? 0 : bw + 1;
    }

    float rl[2];
    rl[0] = 1.0f / ol[0][0];
    rl[1] = 1.0f / ol[1][0];
    __syncthreads();
    // Ksc spans KV flat [0..9216) u16; in-flight chunk-32 DMAs (if any) write
    // slot 2 [16384..) -> disjoint.
    u16* Ksc = &KV[0][0];
#pragma unroll
    for (int qi = 0; qi < 2; ++qi)
#pragma unroll
        for (int dt = 0; dt < 4; ++dt)
#pragma unroll
            for (int jj = 0; jj < 2; ++jj) {
                u32 lo_ = (u32)f2bf(o[qi][dt][2 * jj] * rl[qi]);
                u32 hi_ = (u32)f2bf(o[qi][dt][2 * jj + 1] * rl[qi]);
                *(u32*)(Ksc + (w * 32 + qi * 16 + l16) * OST + dt * 16 + quad * 4 + jj * 2) =
                    lo_ | (hi_ << 16);
            }
    __syncthreads();
    const int b = bh >> 4, h = bh & 15;
#pragma unroll
    for (int i = 0; i < 4; ++i) {
        int idx = i * 256 + t;
        int q = idx >> 3, c = idx & 7;
        uint4 vv = *(const uint4*)(Ksc + q * OST + c * 8);
        *(uint4*)(AO + ((size_t)(b * SS + qt * 128 + q)) * EMBD + h * DH + c * 8) = vv;
    }
}

// ---------------- out projection GEMM: 128x64 tile, BK=64, ring-3, swizzled -
// (R8-proven: 16 K-iterations, 6 DMAs/iter, vmcnt(6), 8-slot row swizzle.)
__global__ __launch_bounds__(256) void gemm_out(
    const u16* __restrict__ Ab,   // [4096][1024]
    const u16* __restrict__ Wb,   // [1024][1024]
    const float* __restrict__ b_out,
    float* __restrict__ Out)
{
    __shared__ u16 AB[3][12288];  // [slot][A 8192 | B 4096]  72 KB (2 blocks/CU)
    const int t = threadIdx.x;
    const int lane = t & 63;
    const int wave = t >> 6;       // wave = M-row group (4x32 rows)
    const int quad = lane >> 4, l16 = lane & 15;
    const int m0 = blockIdx.y * 128, n0 = blockIdx.x * 64;

    // staging: row = i*32 + (t>>3); source slot = (t&7) ^ ((t>>3)&7)
    const int srow = t >> 3;
    const int scol = ((t & 7) ^ (srow & 7)) * 8;
    const u16* gaA[4];
#pragma unroll
    for (int i = 0; i < 4; ++i)
        gaA[i] = Ab + (size_t)(m0 + i * 32 + srow) * EMBD + scol;
    const u16* gbB[2];
#pragma unroll
    for (int i = 0; i < 2; ++i)
        gbB[i] = Wb + (size_t)(n0 + i * 32 + srow) * EMBD + scol;

    f32x4 acc[2][4] = {};

    // prologue: k-tiles 0,1 -> slots 0,1 (6 DMAs each)
#pragma unroll
    for (int p = 0; p < 2; ++p) {
        u16* buf = &AB[p][0];
#pragma unroll
        for (int i = 0; i < 4; ++i)
            GLDS16(gaA[i] + p * 64, buf + i * 2048 + t * 8);
#pragma unroll
        for (int i = 0; i < 2; ++i)
            GLDS16(gbB[i] + p * 64, buf + 8192 + i * 2048 + t * 8);
    }

    int bi = 0, bw = 2;
    for (int it = 0; it < EMBD / 64; ++it) {
        asm volatile("s_waitcnt vmcnt(6)" ::: "memory");
        __syncthreads();
        {   // always-issue tile it+2 (trailing OOB reads stay inside ws: benign)
            int k0 = (it + 2) * 64;
            u16* buf = &AB[bw][0];
#pragma unroll
            for (int i = 0; i < 4; ++i)
                GLDS16(gaA[i] + k0, buf + i * 2048 + t * 8);
#pragma unroll
            for (int i = 0; i < 2; ++i)
                GLDS16(gbB[i] + k0, buf + 8192 + i * 2048 + t * 8);
        }
        const u16* As = &AB[bi][0];
        const u16* Bs = &AB[bi][8192];
        bf16x8 af[2][2], bfr[4][2];
#pragma unroll
        for (int im = 0; im < 2; ++im)
#pragma unroll
            for (int kk = 0; kk < 2; ++kk)
                af[im][kk] = *(const bf16x8*)(As + (wave * 32 + im * 16 + l16) * 64
                                              + (((kk * 4 + quad) ^ (l16 & 7)) * 8));
#pragma unroll
        for (int in = 0; in < 4; ++in)
#pragma unroll
            for (int kk = 0; kk < 2; ++kk)
                bfr[in][kk] = *(const bf16x8*)(Bs + (in * 16 + l16) * 64
                                               + (((kk * 4 + quad) ^ (l16 & 7)) * 8));
#pragma unroll
        for (int im = 0; im < 2; ++im)
#pragma unroll
            for (int in = 0; in < 4; ++in)
#pragma unroll
                for (int kk = 0; kk < 2; ++kk)
                    acc[im][in] = __builtin_amdgcn_mfma_f32_16x16x32_bf16(
                        af[im][kk], bfr[in][kk], acc[im][in], 0, 0, 0);
        bi = (bi == 2) ? 0 : bi + 1;
        bw = (bw == 2) ? 0 : bw + 1;
    }

#pragma unroll
    for (int im = 0; im < 2; ++im) {
        int rbase = m0 + wave * 32 + im * 16 + quad * 4;
#pragma unroll
        for (int in = 0; in < 4; ++in) {
            int col = n0 + in * 16 + l16;
            float bias = b_out[col];
#pragma unroll
            for (int j = 0; j < 4; ++j)
                Out[(size_t)(rbase + j) * EMBD + col] = acc[im][in][j] + bias;
        }
    }
}

extern "C" void kernel_launch(void* const* d_in, const int* in_sizes, int n_in,
                              void* d_out, int out_size, void* d_ws, size_t ws_size,
                              hipStream_t stream)
{
    (void)in_sizes; (void)n_in; (void)out_size; (void)ws_size;
    const float* x     = (const float*)d_in[0];
    const float* W_in  = (const float*)d_in[1];
    const float* b_in  = (const float*)d_in[2];
    const float* W_out = (const float*)d_in[3];
    const float* b_out = (const float*)d_in[4];
    float* out = (float*)d_out;

    char* ws = (char*)d_ws;
    u16* xb  = (u16*)(ws);                          //  8 MB: x bf16 [4096][1024]
    u16* wib = (u16*)(ws + 8u  * 1024 * 1024);      //  6 MB: W_in bf16
    u16* wob = (u16*)(ws + 14u * 1024 * 1024);      //  2 MB: W_out bf16
    u16* Qw  = (u16*)(ws + 16u * 1024 * 1024);      //  8 MB: Q (x log2e/8)
    u16* Kw  = (u16*)(ws + 24u * 1024 * 1024);      //  8 MB: Kf fragment-linear
    u16* Vpw = (u16*)(ws + 32u * 1024 * 1024);      //  8 MB: Vpf frag-linear permuted
    u16* AO  = (u16*)(ws + 40u * 1024 * 1024);      //  8 MB: attn out bf16

    cast_all<<<(NX8 + NWI8 + NWO8) / 256, 256, 0, stream>>>(x, W_in, W_out, xb, wib, wob);
    gemm_qkv<<<dim3(N_QKV / 128, M_TOT / 128), 256, 0, stream>>>(xb, wib, b_in, Qw, Kw, Vpw);
    attn<<<512, 256, 0, stream>>>(Qw, Kw, Vpw, AO);
    gemm_out<<<dim3(EMBD / 64, M_TOT / 128), 256, 0, stream>>>(AO, wob, b_out, out);
}